// Round 8
// baseline (325.112 us; speedup 1.0000x reference)
//
#include <hip/hip_runtime.h>
#include <math.h>

// Problem constants
#define BATCH 32
#define H 512
#define W 512
#define OUTD 502          // 512 - 11 + 1
#define WS 11
#define STRIP 32          // output rows per block
#define INROWS 42         // STRIP + WS - 1 input rows per strip
#define WPAD 80           // per-wave LDS plane width: 64 cols + 10 halo + pad

#define C1F 6.5025f       // (0.01*255)^2
#define C2F 58.5225f      // (0.03*255)^2
#define N_OUT_TOTAL 8064128.0   // 32 * 502 * 502

struct GW { float g[WS]; };
struct F3 { float x, y, z; };   // 12-byte RGB pixel load

// ROUND-16: 4-plane SCALAR LDS payload.
// Round-15 resolved the pressure A/B: fence is register-neutral (124
// VGPR), the float4 payload was the +100 VGPR culprit (4-reg b128 read
// results + float4 store assembly). But the float4 idea's VALU saving
// was real: the h-conv recomputes c*c / fmaf(a,a,..) / a*c at EVERY
// tap (33 VALU/step of redundancy — each column's squares computed by
// 11 threads). This round keeps the saving, drops the pressure:
//   sbuf[2][4][4][WPAD] — four SCALAR planes (a, c, a^2+c^2, a*c).
//   Squares/cross computed ONCE per column at store time (+6 VALU);
//   h-conv tap = 4x ds_read_b32 + 4 FMA (1-reg read granularity, the
//   round-15 allocator profile). Net -27 VALU/step.
// LDS pipe check: 52 DS ops/step x 2 cyc x 16 waves ~ 1.7k cyc per
// 6.2k-cyc step window — not limiting.
// Everything else = round-15 verbatim (proven: absmax 0.0, 124 VGPR):
//   * LDS_FENCE per ROW_STEP — orders the wave-private DS traffic
//     (HW runs DS in wave order; fence pins emitted order across steps).
//     Fixed the round-6/7/9/10 miscompile class.
//   * NO occupancy attributes — launch_bounds(256,4) and
//     waves_per_eu(4,4) both drive the allocator to 64 VGPR + 300-420
//     MB scratch spill (rounds 12/14). Plain launch_bounds(256) only.
//   * rolled 2-chunk output loop + 10-row unrolled tail, ring zero-init,
//     1-row-ahead raw RGB prefetch, luma as 3 FMAs, rcp divide, f32
//     accumulator, 12-byte RGB struct loads.

#define LDS_FENCE() asm volatile("" ::: "memory")

__device__ __forceinline__ float luma3(float r, float g, float b) {
    // y = ((x+1)*127.5) dot w / 256 + 16  ==  x dot W + K, all f32-folded
    constexpr float W0 = 127.5f * 65.738f  / 256.f;
    constexpr float W1 = 127.5f * 129.057f / 256.f;
    constexpr float W2 = 127.5f * 25.064f  / 256.f;
    constexpr float K0 = 127.5f * 65.738f  / 256.f
                       + 127.5f * 129.057f / 256.f
                       + 127.5f * 25.064f  / 256.f + 16.f;
    return fmaf(r, W0, fmaf(g, W1, fmaf(b, W2, K0)));
}

// Streaming SSIM, one thread per output column, 32-row strip per block,
// wave-private LDS (no barriers in the row loop; one compiler fence per
// row step).
__global__ __launch_bounds__(256) void ssim_stream_kernel(
    const float* __restrict__ img1, const float* __restrict__ img2,
    double* __restrict__ acc_out, GW wv)
{
    // parity x wave x plane{a, c, a^2+c^2, a*c} x width
    __shared__ float sbuf[2][4][4][WPAD];
    __shared__ double wsum[4];

    const int t    = threadIdx.x;
    const int lane = t & 63;
    const int wvid = t >> 6;
    const int cw = blockIdx.x * 256 + wvid * 64;  // wave's first column
    const int ox = cw + lane;                     // owned output column
    const int r0 = blockIdx.y * STRIP;
    const int b  = blockIdx.z;

    const bool colok = (ox < OUTD);
    const bool halo  = (lane < 10) && ((cw + 64 + lane) < W);
    const size_t imgbase = (size_t)b * (H * W * 3) + (size_t)r0 * (W * 3);
    const int colA = (cw + lane) * 3;             // main col (always < W)
    const int colB = (cw + 64 + lane) * 3;        // halo col

    // Raw RGB pipeline registers: c* = row iy+1 (ready), n* = row iy+2 (in flight)
    float cA0, cA1, cA2, cB0, cB1, cB2, cC0, cC1, cC2, cD0, cD1, cD2;
    float nA0, nA1, nA2, nB0, nB1, nB2, nC0, nC1, nC2, nD0, nD1, nD2;

// Issue raw loads for strip row IY into 12 named registers (NO conversion
// here — keeping load->use distance at one full row step).
#define LOAD_RAW(IY, A0,A1,A2, B0,B1,B2, C0,C1v,C2v, D0,D1,D2)            \
    {                                                                     \
        A0=A1=A2=B0=B1=B2=C0=C1v=C2v=D0=D1=D2 = 0.f;                      \
        if ((IY) < INROWS && (r0 + (IY)) < H) {                           \
            const float* _q1 = img1 + imgbase + (size_t)((IY) * (W * 3)); \
            const float* _q2 = img2 + imgbase + (size_t)((IY) * (W * 3)); \
            const F3 _pa = *reinterpret_cast<const F3*>(_q1 + colA);      \
            const F3 _pb = *reinterpret_cast<const F3*>(_q2 + colA);      \
            A0 = _pa.x; A1 = _pa.y; A2 = _pa.z;                           \
            B0 = _pb.x; B1 = _pb.y; B2 = _pb.z;                           \
            if (halo) {                                                   \
                const F3 _pc = *reinterpret_cast<const F3*>(_q1 + colB);  \
                const F3 _pd = *reinterpret_cast<const F3*>(_q2 + colB);  \
                C0  = _pc.x; C1v = _pc.y; C2v = _pc.z;                    \
                D0  = _pd.x; D1  = _pd.y; D2  = _pd.z;                    \
            }                                                             \
        }                                                                 \
    }

// Convert current raw regs (row IY) to luma + derived planes and store to
// LDS parity IY&1. Squares/cross computed ONCE per column here (scalar
// b32 stores — 1-reg granularity for the allocator).
#define STORE_ROW(IY)                                                     \
    {                                                                     \
        const int _p = (IY) & 1;                                          \
        {                                                                 \
            const float _a = luma3(cA0, cA1, cA2);                        \
            const float _c = luma3(cB0, cB1, cB2);                        \
            sbuf[_p][wvid][0][lane] = _a;                                 \
            sbuf[_p][wvid][1][lane] = _c;                                 \
            sbuf[_p][wvid][2][lane] = fmaf(_a, _a, _c * _c);              \
            sbuf[_p][wvid][3][lane] = _a * _c;                            \
        }                                                                 \
        if (lane < 10) {                                                  \
            const float _a = luma3(cC0, cC1, cC2);                        \
            const float _c = luma3(cD0, cD1, cD2);                        \
            sbuf[_p][wvid][0][64 + lane] = _a;                            \
            sbuf[_p][wvid][1][64 + lane] = _c;                            \
            sbuf[_p][wvid][2][64 + lane] = fmaf(_a, _a, _c * _c);         \
            sbuf[_p][wvid][3][64 + lane] = _a * _c;                       \
        }                                                                 \
    }

#define ROTATE_RAW()                                                      \
    {                                                                     \
        cA0 = nA0; cA1 = nA1; cA2 = nA2; cB0 = nB0; cB1 = nB1; cB2 = nB2; \
        cC0 = nC0; cC1 = nC1; cC2 = nC2; cD0 = nD0; cD1 = nD1; cD2 = nD2; \
    }

// One row step: prefetch raw row IY+2; convert+store row IY+1; h-conv row
// IY from LDS into H0..H3. ONE fence at the top: all DS ops of the
// previous step are emitted before all DS ops of this step (covers both
// cross-step hazard directions); within the step, stores (parity ~rb)
// and reads (parity rb) touch opposite buffers — scheduler is free.
// h-conv tap = 4x ds_read_b32 + 4 FMA (no per-tap square recompute).
#define ROW_STEP(IY, H0, H1, H2, H3)                                      \
    {                                                                     \
        LDS_FENCE();                                                      \
        LOAD_RAW((IY) + 2, nA0,nA1,nA2, nB0,nB1,nB2,                      \
                           nC0,nC1,nC2, nD0,nD1,nD2);                     \
        STORE_ROW((IY) + 1);                                              \
        ROTATE_RAW();                                                     \
        {                                                                 \
            const int _rb = (IY) & 1;                                     \
            float _h0 = 0.f, _h1 = 0.f, _h2 = 0.f, _h3 = 0.f;             \
            _Pragma("unroll")                                             \
            for (int _k = 0; _k < WS; ++_k) {                             \
                const float _gk = wv.g[_k];                               \
                _h0 = fmaf(_gk, sbuf[_rb][wvid][0][lane + _k], _h0);      \
                _h1 = fmaf(_gk, sbuf[_rb][wvid][1][lane + _k], _h1);      \
                _h2 = fmaf(_gk, sbuf[_rb][wvid][2][lane + _k], _h2);      \
                _h3 = fmaf(_gk, sbuf[_rb][wvid][3][lane + _k], _h3);      \
            }                                                             \
            H0 = _h0; H1 = _h1; H2 = _h2; H3 = _h3;                       \
        }                                                                 \
    }

    // Register ring: slot s holds h-conv of input row r with r % 11 == s.
    // Zero-init ALL slots — no undef values anywhere, ever.
    float rm1[WS], rm2[WS], rq[WS], rx[WS];
    #pragma unroll
    for (int s = 0; s < WS; ++s) {
        rm1[s] = 0.f; rm2[s] = 0.f; rq[s] = 0.f; rx[s] = 0.f;
    }

    // Prologue: raw row 0 -> c; raw row 1 -> n (in flight); luma row 0 -> LDS.
    LOAD_RAW(0, cA0,cA1,cA2, cB0,cB1,cB2, cC0,cC1,cC2, cD0,cD1,cD2);
    LOAD_RAW(1, nA0,nA1,nA2, nB0,nB1,nB2, nC0,nC1,nC2, nD0,nD1,nD2);
    STORE_ROW(0);                       // one-time stall on row-0 loads
    ROTATE_RAW();                       // c = raw row 1

    // Fill ring with input rows 0..9 (slots 0..9).
    #pragma unroll
    for (int j = 0; j < 10; ++j)
        ROW_STEP(j, rm1[j], rm2[j], rq[j], rx[j]);

    float local = 0.f;

// Output row OY (JM == OY % 11, compile-time): insert row OY+10 at slot
// (JM+10)%11, then vertical 11-tap conv over slots (JM+k)%11 and SSIM.
#define DO_ROW(OY, JM)                                                    \
    {                                                                     \
        ROW_STEP((OY) + 10,                                               \
                 rm1[((JM) + 10) % WS], rm2[((JM) + 10) % WS],            \
                 rq[((JM) + 10) % WS],  rx[((JM) + 10) % WS]);            \
        float _mu1 = 0.f, _mu2 = 0.f, _eq = 0.f, _ex = 0.f;               \
        _Pragma("unroll")                                                 \
        for (int _k = 0; _k < WS; ++_k) {                                 \
            const float _gk = wv.g[_k];                                   \
            const int _s = ((JM) + _k) % WS;                              \
            _mu1 = fmaf(_gk, rm1[_s], _mu1);                              \
            _mu2 = fmaf(_gk, rm2[_s], _mu2);                              \
            _eq  = fmaf(_gk, rq[_s],  _eq);                               \
            _ex  = fmaf(_gk, rx[_s],  _ex);                               \
        }                                                                 \
        if (colok && (r0 + (OY)) < OUTD) {                                \
            const float _m1s = _mu1 * _mu1;                               \
            const float _m2s = _mu2 * _mu2;                               \
            const float _m12 = _mu1 * _mu2;                               \
            const float _num = (2.f * _m12 + C1F) *                       \
                               (2.f * (_ex - _m12) + C2F);                \
            const float _den = (_m1s + _m2s + C1F) *                      \
                               ((_eq - _m1s - _m2s) + C2F);               \
            local = fmaf(_num, __builtin_amdgcn_rcpf(_den), local);       \
        }                                                                 \
    }

    // Output rows 0..21: ROLLED 2-chunk loop; rows 22..31 unrolled tail.
    // Ring indices stay compile-time (JM=j).
    #pragma unroll 1
    for (int c = 0; c < 2; ++c) {
        const int base = c * 11;
        #pragma unroll
        for (int j = 0; j < 11; ++j)
            DO_ROW(base + j, j);
    }
    #pragma unroll
    for (int j = 0; j < 10; ++j)
        DO_ROW(22 + j, j);

    // Block reduction: wave shuffle (f32 tree) -> LDS (double) -> one atomic.
    for (int off = 32; off > 0; off >>= 1)
        local += __shfl_down(local, off, 64);
    if (lane == 0) wsum[wvid] = (double)local;
    __syncthreads();
    if (t == 0) {
        const double s = wsum[0] + wsum[1] + wsum[2] + wsum[3];
        atomicAdd(acc_out, s);
    }
}

__global__ void ssim_finalize_kernel(const double* __restrict__ acc,
                                     float* __restrict__ out)
{
    out[0] = (float)(acc[0] / N_OUT_TOTAL);
}

extern "C" void kernel_launch(void* const* d_in, const int* in_sizes, int n_in,
                              void* d_out, int out_size, void* d_ws, size_t ws_size,
                              hipStream_t stream) {
    const float* img1 = (const float*)d_in[0];
    const float* img2 = (const float*)d_in[1];
    float* out = (float*)d_out;
    double* acc = (double*)d_ws;

    // Gaussian window, computed exactly as the numpy reference (float32 ops)
    GW w;
    {
        float g[WS];
        float s = 0.f;
        for (int i = 0; i < WS; ++i) {
            const float x = (float)(i - WS / 2);
            g[i] = expf(-(x * x) / (2.f * 1.5f * 1.5f));
            s += g[i];
        }
        for (int i = 0; i < WS; ++i) w.g[i] = g[i] / s;
    }

    hipMemsetAsync(d_ws, 0, sizeof(double), stream);

    dim3 grid(2, (OUTD + STRIP - 1) / STRIP, BATCH);   // 2 x 16 x 32 = 1024 blocks
    ssim_stream_kernel<<<grid, 256, 0, stream>>>(img1, img2, acc, w);
    ssim_finalize_kernel<<<1, 1, 0, stream>>>(acc, out);
}

// Round 9
// 244.679 us; speedup vs baseline: 1.3287x; 1.3287x over previous
//
#include <hip/hip_runtime.h>
#include <math.h>

// Problem constants
#define BATCH 32
#define H 512
#define W 512
#define OUTD 502          // 512 - 11 + 1
#define WS 11
#define STRIP 32          // output rows per block
#define INROWS 42         // STRIP + WS - 1 input rows per strip
#define WPAD 80           // per-wave LDS width in float2 units: 64 + 10 halo + pad

#define C1F 6.5025f       // (0.01*255)^2
#define C2F 58.5225f      // (0.03*255)^2
#define N_OUT_TOTAL 8064128.0   // 32 * 502 * 502

struct GW { float g[WS]; };
struct F3 { float x, y, z; };   // 12-byte RGB pixel load
typedef float v2f __attribute__((ext_vector_type(2)));

// ROUND-17: (s,d) packed-pair transform on the round-15 base.
// Pressure law established by r13/r15/r16: VGPR tracks the NUMBER of
// independent LDS reads per step (22 reads -> 124 VGPR @109us; 44 reads
// -> 220-236 VGPR @180-196us, regardless of b32/b128 width). So the
// square-recompute fat (33 VALU/step) must be removed WITHOUT adding
// reads. Transform: store s=a+c, d=a-c as ONE float2 per column.
//   conv linear:  S=conv(s), D=conv(d)  -> mu1=(S+D)/2, mu2=(S-D)/2
//   s^2+d^2=2(a^2+c^2), s^2-d^2=4ac     -> eq=(Q2+D2)/2, ex=(Q2-D2)/4
// Per tap: 1 ds_read_b64 + {(S,D)+=g*(s,d); t=(s,d)^2; (Q2,D2)+=g*t}
// — all packed-f32 pairs (v_pk_fma_f32/v_pk_mul_f32 via
// __builtin_elementwise_fma on float2). 1 DS + 3 VALU/tap vs r15's
// 2 DS + 7. V-conv: 22 packed FMA vs 44 scalar. Ring unchanged at 44
// regs (11 x float2 x 2 pairs). Reads/step 22 -> 11 (pressure-safe
// direction). Even scalarized this is a strict instruction cut.
// Everything else = round-15 verbatim (proven: absmax 0.0, 124 VGPR,
// 109 us):
//   * LDS_FENCE per ROW_STEP — orders wave-private DS traffic (HW runs
//     DS in wave order; fence pins emitted order across steps). Fixed
//     the r6/7/9/10 miscompile class.
//   * NO occupancy attributes (launch_bounds(256,4) / waves_per_eu(4,4)
//     both => 64 VGPR + 300-420 MB scratch spill, r12/r14).
//   * rolled 2-chunk output loop + 10-row unrolled tail, ring zero-init,
//     1-row-ahead raw RGB prefetch, luma as 3 FMAs, rcp divide, f32
//     accumulator, 12-byte RGB struct loads.

#define LDS_FENCE() asm volatile("" ::: "memory")

__device__ __forceinline__ float luma3(float r, float g, float b) {
    // y = ((x+1)*127.5) dot w / 256 + 16  ==  x dot W + K, all f32-folded
    constexpr float W0 = 127.5f * 65.738f  / 256.f;
    constexpr float W1 = 127.5f * 129.057f / 256.f;
    constexpr float W2 = 127.5f * 25.064f  / 256.f;
    constexpr float K0 = 127.5f * 65.738f  / 256.f
                       + 127.5f * 129.057f / 256.f
                       + 127.5f * 25.064f  / 256.f + 16.f;
    return fmaf(r, W0, fmaf(g, W1, fmaf(b, W2, K0)));
}

// Streaming SSIM, one thread per output column, 32-row strip per block,
// wave-private LDS (no barriers in the row loop; one compiler fence per
// row step).
__global__ __launch_bounds__(256) void ssim_stream_kernel(
    const float* __restrict__ img1, const float* __restrict__ img2,
    double* __restrict__ acc_out, GW wv)
{
    // parity x wave x column, packed (s, d) = (a+c, a-c)
    __shared__ v2f sbuf[2][4][WPAD];
    __shared__ double wsum[4];

    const int t    = threadIdx.x;
    const int lane = t & 63;
    const int wvid = t >> 6;
    const int cw = blockIdx.x * 256 + wvid * 64;  // wave's first column
    const int ox = cw + lane;                     // owned output column
    const int r0 = blockIdx.y * STRIP;
    const int b  = blockIdx.z;

    const bool colok = (ox < OUTD);
    const bool halo  = (lane < 10) && ((cw + 64 + lane) < W);
    const size_t imgbase = (size_t)b * (H * W * 3) + (size_t)r0 * (W * 3);
    const int colA = (cw + lane) * 3;             // main col (always < W)
    const int colB = (cw + 64 + lane) * 3;        // halo col

    // Raw RGB pipeline registers: c* = row iy+1 (ready), n* = row iy+2 (in flight)
    float cA0, cA1, cA2, cB0, cB1, cB2, cC0, cC1, cC2, cD0, cD1, cD2;
    float nA0, nA1, nA2, nB0, nB1, nB2, nC0, nC1, nC2, nD0, nD1, nD2;

// Issue raw loads for strip row IY into 12 named registers (NO conversion
// here — keeping load->use distance at one full row step).
#define LOAD_RAW(IY, A0,A1,A2, B0,B1,B2, C0,C1v,C2v, D0,D1,D2)            \
    {                                                                     \
        A0=A1=A2=B0=B1=B2=C0=C1v=C2v=D0=D1=D2 = 0.f;                      \
        if ((IY) < INROWS && (r0 + (IY)) < H) {                           \
            const float* _q1 = img1 + imgbase + (size_t)((IY) * (W * 3)); \
            const float* _q2 = img2 + imgbase + (size_t)((IY) * (W * 3)); \
            const F3 _pa = *reinterpret_cast<const F3*>(_q1 + colA);      \
            const F3 _pb = *reinterpret_cast<const F3*>(_q2 + colA);      \
            A0 = _pa.x; A1 = _pa.y; A2 = _pa.z;                           \
            B0 = _pb.x; B1 = _pb.y; B2 = _pb.z;                           \
            if (halo) {                                                   \
                const F3 _pc = *reinterpret_cast<const F3*>(_q1 + colB);  \
                const F3 _pd = *reinterpret_cast<const F3*>(_q2 + colB);  \
                C0  = _pc.x; C1v = _pc.y; C2v = _pc.z;                    \
                D0  = _pd.x; D1  = _pd.y; D2  = _pd.z;                    \
            }                                                             \
        }                                                                 \
    }

// Convert current raw regs (row IY) to lumas a,c then pack (s,d)=(a+c,a-c)
// into ONE float2 per column (single ds_write_b64). LDS parity IY&1.
#define STORE_ROW(IY)                                                     \
    {                                                                     \
        const int _p = (IY) & 1;                                          \
        {                                                                 \
            const float _a = luma3(cA0, cA1, cA2);                        \
            const float _c = luma3(cB0, cB1, cB2);                        \
            v2f _v; _v.x = _a + _c; _v.y = _a - _c;                       \
            sbuf[_p][wvid][lane] = _v;                                    \
        }                                                                 \
        if (lane < 10) {                                                  \
            const float _a = luma3(cC0, cC1, cC2);                        \
            const float _c = luma3(cD0, cD1, cD2);                        \
            v2f _v; _v.x = _a + _c; _v.y = _a - _c;                       \
            sbuf[_p][wvid][64 + lane] = _v;                               \
        }                                                                 \
    }

#define ROTATE_RAW()                                                      \
    {                                                                     \
        cA0 = nA0; cA1 = nA1; cA2 = nA2; cB0 = nB0; cB1 = nB1; cB2 = nB2; \
        cC0 = nC0; cC1 = nC1; cC2 = nC2; cD0 = nD0; cD1 = nD1; cD2 = nD2; \
    }

// One row step: prefetch raw row IY+2; convert+store row IY+1; h-conv row
// IY from LDS into packed pairs HSD=(S,D), HQD=(Q2,D2). ONE fence at the
// top: all DS ops of the previous step emitted before all of this step
// (covers both cross-step hazard directions); within the step, stores
// (parity ~rb) and reads (parity rb) touch opposite buffers.
// h-conv tap = 1x ds_read_b64 + 3 packed-f32 ops (pk_fma/pk_mul).
#define ROW_STEP(IY, HSD, HQD)                                            \
    {                                                                     \
        LDS_FENCE();                                                      \
        LOAD_RAW((IY) + 2, nA0,nA1,nA2, nB0,nB1,nB2,                      \
                           nC0,nC1,nC2, nD0,nD1,nD2);                     \
        STORE_ROW((IY) + 1);                                              \
        ROTATE_RAW();                                                     \
        {                                                                 \
            const int _rb = (IY) & 1;                                     \
            v2f _hm = {0.f, 0.f}, _hq = {0.f, 0.f};                       \
            _Pragma("unroll")                                             \
            for (int _k = 0; _k < WS; ++_k) {                             \
                const float _gk = wv.g[_k];                               \
                const v2f _gv = {_gk, _gk};                               \
                const v2f _pv = sbuf[_rb][wvid][lane + _k];               \
                _hm = __builtin_elementwise_fma(_gv, _pv, _hm);           \
                const v2f _tv = _pv * _pv;                                \
                _hq = __builtin_elementwise_fma(_gv, _tv, _hq);           \
            }                                                             \
            HSD = _hm; HQD = _hq;                                         \
        }                                                                 \
    }

    // Register ring: slot s holds packed h-conv pairs of input row r with
    // r % 11 == s. Zero-init ALL slots — no undef values anywhere, ever.
    v2f rSD[WS], rQD[WS];
    #pragma unroll
    for (int s = 0; s < WS; ++s) {
        rSD[s] = (v2f){0.f, 0.f}; rQD[s] = (v2f){0.f, 0.f};
    }

    // Prologue: raw row 0 -> c; raw row 1 -> n (in flight); row 0 -> LDS.
    LOAD_RAW(0, cA0,cA1,cA2, cB0,cB1,cB2, cC0,cC1,cC2, cD0,cD1,cD2);
    LOAD_RAW(1, nA0,nA1,nA2, nB0,nB1,nB2, nC0,nC1,nC2, nD0,nD1,nD2);
    STORE_ROW(0);                       // one-time stall on row-0 loads
    ROTATE_RAW();                       // c = raw row 1

    // Fill ring with input rows 0..9 (slots 0..9).
    #pragma unroll
    for (int j = 0; j < 10; ++j)
        ROW_STEP(j, rSD[j], rQD[j]);

    float local = 0.f;

// Output row OY (JM == OY % 11, compile-time): insert row OY+10 at slot
// (JM+10)%11, then packed vertical 11-tap conv over slots (JM+k)%11,
// unpack via the (s,d) algebra, and SSIM.
#define DO_ROW(OY, JM)                                                    \
    {                                                                     \
        ROW_STEP((OY) + 10,                                               \
                 rSD[((JM) + 10) % WS], rQD[((JM) + 10) % WS]);           \
        v2f _MU = {0.f, 0.f}, _EX = {0.f, 0.f};                           \
        _Pragma("unroll")                                                 \
        for (int _k = 0; _k < WS; ++_k) {                                 \
            const float _gk = wv.g[_k];                                   \
            const v2f _gv = {_gk, _gk};                                   \
            const int _s = ((JM) + _k) % WS;                              \
            _MU = __builtin_elementwise_fma(_gv, rSD[_s], _MU);           \
            _EX = __builtin_elementwise_fma(_gv, rQD[_s], _EX);           \
        }                                                                 \
        if (colok && (r0 + (OY)) < OUTD) {                                \
            const float _mu1 = 0.5f * (_MU.x + _MU.y);                    \
            const float _mu2 = 0.5f * (_MU.x - _MU.y);                    \
            const float _eq  = 0.5f  * (_EX.x + _EX.y);                   \
            const float _ex  = 0.25f * (_EX.x - _EX.y);                   \
            const float _m1s = _mu1 * _mu1;                               \
            const float _m2s = _mu2 * _mu2;                               \
            const float _m12 = _mu1 * _mu2;                               \
            const float _num = (2.f * _m12 + C1F) *                       \
                               (2.f * (_ex - _m12) + C2F);                \
            const float _den = (_m1s + _m2s + C1F) *                      \
                               ((_eq - _m1s - _m2s) + C2F);               \
            local = fmaf(_num, __builtin_amdgcn_rcpf(_den), local);       \
        }                                                                 \
    }

    // Output rows 0..21: ROLLED 2-chunk loop; rows 22..31 unrolled tail.
    // Ring indices stay compile-time (JM=j).
    #pragma unroll 1
    for (int c = 0; c < 2; ++c) {
        const int base = c * 11;
        #pragma unroll
        for (int j = 0; j < 11; ++j)
            DO_ROW(base + j, j);
    }
    #pragma unroll
    for (int j = 0; j < 10; ++j)
        DO_ROW(22 + j, j);

    // Block reduction: wave shuffle (f32 tree) -> LDS (double) -> one atomic.
    for (int off = 32; off > 0; off >>= 1)
        local += __shfl_down(local, off, 64);
    if (lane == 0) wsum[wvid] = (double)local;
    __syncthreads();
    if (t == 0) {
        const double s = wsum[0] + wsum[1] + wsum[2] + wsum[3];
        atomicAdd(acc_out, s);
    }
}

__global__ void ssim_finalize_kernel(const double* __restrict__ acc,
                                     float* __restrict__ out)
{
    out[0] = (float)(acc[0] / N_OUT_TOTAL);
}

extern "C" void kernel_launch(void* const* d_in, const int* in_sizes, int n_in,
                              void* d_out, int out_size, void* d_ws, size_t ws_size,
                              hipStream_t stream) {
    const float* img1 = (const float*)d_in[0];
    const float* img2 = (const float*)d_in[1];
    float* out = (float*)d_out;
    double* acc = (double*)d_ws;

    // Gaussian window, computed exactly as the numpy reference (float32 ops)
    GW w;
    {
        float g[WS];
        float s = 0.f;
        for (int i = 0; i < WS; ++i) {
            const float x = (float)(i - WS / 2);
            g[i] = expf(-(x * x) / (2.f * 1.5f * 1.5f));
            s += g[i];
        }
        for (int i = 0; i < WS; ++i) w.g[i] = g[i] / s;
    }

    hipMemsetAsync(d_ws, 0, sizeof(double), stream);

    dim3 grid(2, (OUTD + STRIP - 1) / STRIP, BATCH);   // 2 x 16 x 32 = 1024 blocks
    ssim_stream_kernel<<<grid, 256, 0, stream>>>(img1, img2, acc, w);
    ssim_finalize_kernel<<<1, 1, 0, stream>>>(acc, out);
}